// Round 1
// 503.080 us; speedup vs baseline: 1.0213x; 1.0213x over previous
//
#include <hip/hip_runtime.h>
#include <math.h>

#define D 2048
#define NS 8
#define BTOT 16384

// ---- d_out layout (floats): read[B,D] | attn[B,8] | alpha | new_state[8,D] | new_fast[8,D]
#define ATTN_OFF  ((size_t)BTOT * D)
#define ALPHA_OFF (ATTN_OFF + (size_t)BTOT * NS)
#define STATE_OFF (ALPHA_OFF + 1)
#define FAST_OFF  (STATE_OFF + (size_t)NS * D)

// ---- ws layout (float offsets) — same footprint as previous version
#define WS_SM    0         // 16384 : state+fast
#define WS_KPX   16384     // 18432 : [9][2048] rows 0..7 = keys@Wr, row 8 = wc_h
#define WS_GS    34816     // 16384 : GS = attn.T @ read   (atomic accum)
#define WS_PB    51200     // 16384 : P = attn.T @ (h+nm)  (atomic accum)
#define WS_LB    215040    // 8     : keys @ br
#define WS_SWC   215048    // 8     : Sm @ wc_r
#define WS_GALL  215056    // 80    : [64..71]=colsum, [72]=addsum (G block unused now)

// ---- Z: sm = state+fast ; zero kpx rows 0..7, GS, P, lb/swc/gall ; copy wc_h to kpx row 8
__global__ void __launch_bounds__(256) kZ(const float* __restrict__ st, const float* __restrict__ fa,
                                          const float* __restrict__ Wc, float* __restrict__ ws) {
  int i = blockIdx.x * 256 + threadIdx.x;
  if (i < 16384) {
    ws[WS_SM + i] = st[i] + fa[i];
  } else if (i < 32768) {
    ws[WS_KPX + (i - 16384)] = 0.f;                       // kpx rows 0..7
  } else if (i < 34816) {
    ws[WS_KPX + 16384 + (i - 32768)] = Wc[i - 32768];     // kpx row 8 = wc_h
  } else if (i < 51200) {
    ws[WS_GS + (i - 34816)] = 0.f;
  } else if (i < 67584) {
    ws[WS_PB + (i - 51200)] = 0.f;
  } else if (i < 67680) {
    ws[WS_LB + (i - 67584)] = 0.f;                        // lb(8) | swc(8) | gall(80)
  }
}

// ---- A: kpx[s][e] += sum_{d in chunk} keys[s][d] * Wr[d][e]   (atomic, 256 blocks)
__global__ void __launch_bounds__(256) kA(const float* __restrict__ keys,
                                          const float* __restrict__ Wr,
                                          float* __restrict__ kpx) {
  int e = blockIdx.x * 256 + threadIdx.x;
  int d0 = blockIdx.y * 64;
  float acc[NS] = {0.f,0.f,0.f,0.f,0.f,0.f,0.f,0.f};
  for (int d = d0; d < d0 + 64; ++d) {
    float wv = Wr[(size_t)d * D + e];
#pragma unroll
    for (int s = 0; s < NS; ++s) acc[s] += keys[s * D + d] * wv;
  }
#pragma unroll
  for (int s = 0; s < NS; ++s) atomicAdd(&kpx[s * D + e], acc[s]);
}

// ---- C: lb[s] = keys[s].br ; swc[s] = Sm[s].wc_r   (8 blocks, atomic accum)
__global__ void __launch_bounds__(256) kC(const float* __restrict__ keys,
                                          const float* __restrict__ br,
                                          const float* __restrict__ Wc,
                                          const float* __restrict__ sm,
                                          float* __restrict__ lb, float* __restrict__ swc) {
  int t = threadIdx.x;
  int idx = blockIdx.x * 256 + t;
  float brv = br[idx];
  float wcr = Wc[D + idx];
  float v[16];
#pragma unroll
  for (int s = 0; s < NS; ++s) {
    v[s]     = keys[s * D + idx] * brv;
    v[8 + s] = sm[s * D + idx] * wcr;
  }
#pragma unroll
  for (int off = 32; off > 0; off >>= 1) {
#pragma unroll
    for (int k = 0; k < 16; ++k) v[k] += __shfl_down(v[k], off);
  }
  __shared__ float red[4 * 16];
  int lane = t & 63, wid = t >> 6;
  if (lane == 0) {
#pragma unroll
    for (int k = 0; k < 16; ++k) red[wid * 16 + k] = v[k];
  }
  __syncthreads();
  if (t < 16) {
    float tot = red[t] + red[16 + t] + red[32 + t] + red[48 + t];
    if (t < 8) atomicAdd(&lb[t], tot); else atomicAdd(&swc[t - 8], tot);
  }
}

// ---- 1: fused logits + softmax + attn + colsum/addsum.
//  One wave per row: lane covers 32 cols (8 float4), kpx (9x2048 = 73.7KB) staged in LDS once.
//  Butterfly-xor reduce -> every lane holds all 9 dot products -> redundant softmax, lane0 stores.
__global__ void __launch_bounds__(256) k1aF(const float* __restrict__ h,
                                            const float* __restrict__ kpx,
                                            const float* __restrict__ lb, const float* __restrict__ swc,
                                            const float* __restrict__ bc,
                                            float* __restrict__ attn, float* __restrict__ gall) {
  __shared__ float4 kl[9 * 512];          // 73728 B
  __shared__ float red2[4 * 9];
  int t = threadIdx.x;
  const float4* kp4 = (const float4*)kpx;
  for (int i = t; i < 4608; i += 256) kl[i] = kp4[i];
  __syncthreads();

  int w = t >> 6, lane = t & 63;
  int row0 = blockIdx.x * 32 + w * 8;
  float lbv[8], swv[8];
#pragma unroll
  for (int s = 0; s < NS; ++s) { lbv[s] = lb[s]; swv[s] = swc[s]; }
  float bc0 = bc[0];
  float cs[9] = {0.f,0.f,0.f,0.f,0.f,0.f,0.f,0.f,0.f};

  for (int r = 0; r < 8; ++r) {
    int row = row0 + r;
    const float4* h4 = (const float4*)h + (size_t)row * 512;
    float4 hv[8];
#pragma unroll
    for (int j = 0; j < 8; ++j) hv[j] = h4[lane + 64 * j];
    float acc[9] = {0.f,0.f,0.f,0.f,0.f,0.f,0.f,0.f,0.f};
#pragma unroll
    for (int j = 0; j < 8; ++j) {
#pragma unroll
      for (int s = 0; s < 9; ++s) {
        float4 kv = kl[s * 512 + lane + 64 * j];
        acc[s] += hv[j].x * kv.x + hv[j].y * kv.y + hv[j].z * kv.z + hv[j].w * kv.w;
      }
    }
#pragma unroll
    for (int off = 32; off > 0; off >>= 1) {
#pragma unroll
      for (int s = 0; s < 9; ++s) acc[s] += __shfl_xor(acc[s], off);
    }
    // softmax over acc[0..7] (+lb), ctrl logit from acc[8]
    float lg[8]; float m = -1e30f;
#pragma unroll
    for (int s = 0; s < NS; ++s) { lg[s] = acc[s] + lbv[s]; m = fmaxf(m, lg[s]); }
    float sum = 0.f;
#pragma unroll
    for (int s = 0; s < NS; ++s) { lg[s] = expf(lg[s] - m); sum += lg[s]; }
    float inv = 1.f / sum;
    float x = acc[8] + bc0;
#pragma unroll
    for (int s = 0; s < NS; ++s) { lg[s] *= inv; x += lg[s] * swv[s]; cs[s] += lg[s]; }
    float add = 1.f / (1.f + expf(-x));
    cs[8] += add;
    if (lane == 0) {
      float4* ao = (float4*)(attn + (size_t)row * NS);
      ao[0] = make_float4(lg[0], lg[1], lg[2], lg[3]);
      ao[1] = make_float4(lg[4], lg[5], lg[6], lg[7]);
    }
  }
  if (lane == 0) {
#pragma unroll
    for (int k = 0; k < 9; ++k) red2[w * 9 + k] = cs[k];
  }
  __syncthreads();
  if (t < 9) {
    float tot = red2[t] + red2[9 + t] + red2[18 + t] + red2[27 + t];
    atomicAdd(&gall[64 + t], tot);
  }
}

static __device__ __forceinline__ float4 f4fma(float s, float4 a, float4 c) {
  c.x += s * a.x; c.y += s * a.y; c.z += s * a.z; c.w += s * a.w; return c;
}

// ---- 2: read = attn @ Sm (streamed), P += attn.T @ (h+nm), GS += attn.T @ read.
//  Grid (8 col-chunks, 128 row-chunks) = 1024 blocks (4/CU).
__global__ void __launch_bounds__(256, 3) k2n(const float* __restrict__ h, const float* __restrict__ nm,
                                              const float* __restrict__ sm, const float* __restrict__ attn,
                                              float* __restrict__ readout, float* __restrict__ pb,
                                              float* __restrict__ gsb) {
  __shared__ float4 lp[4][NS][64];
  int t = threadIdx.x;
  int c4 = t & 63, r4 = t >> 6;
  int chunk = blockIdx.x, rc = blockIdx.y;
  int fbase = chunk * 64 + c4;
  const float4* sm4 = (const float4*)sm;
  float4 S[NS];
#pragma unroll
  for (int s = 0; s < NS; ++s) S[s] = sm4[s * 512 + fbase];
  float4 P[NS], Q[NS];
#pragma unroll
  for (int s = 0; s < NS; ++s) { P[s] = make_float4(0.f,0.f,0.f,0.f); Q[s] = make_float4(0.f,0.f,0.f,0.f); }
  int rowbase = rc * 128;
  for (int it = 0; it < 32; ++it) {
    int row = rowbase + it * 4 + r4;
    float4 hv = ((const float4*)h)[(size_t)row * 512 + fbase];
    float4 nv = ((const float4*)nm)[(size_t)row * 512 + fbase];
    const float* ar = attn + (size_t)row * NS;
    float a[NS];
#pragma unroll
    for (int s = 0; s < NS; ++s) a[s] = ar[s];
    float4 wv = make_float4(hv.x + nv.x, hv.y + nv.y, hv.z + nv.z, hv.w + nv.w);
    float4 rd = make_float4(0.f, 0.f, 0.f, 0.f);
#pragma unroll
    for (int s = 0; s < NS; ++s) {
      rd = f4fma(a[s], S[s], rd);
      P[s] = f4fma(a[s], wv, P[s]);
    }
#pragma unroll
    for (int s = 0; s < NS; ++s) Q[s] = f4fma(a[s], rd, Q[s]);
    ((float4*)readout)[(size_t)row * 512 + fbase] = rd;
  }
  // round 1: reduce P across 4 row-subgroups -> atomics into pb
#pragma unroll
  for (int s = 0; s < NS; ++s) lp[r4][s][c4] = P[s];
  __syncthreads();
  for (int k = t; k < 512; k += 256) {
    int s = k >> 6, c = k & 63;
    float4 a0 = lp[0][s][c], b0 = lp[1][s][c], c0 = lp[2][s][c], d0 = lp[3][s][c];
    float4 v = make_float4(a0.x + b0.x + c0.x + d0.x, a0.y + b0.y + c0.y + d0.y,
                           a0.z + b0.z + c0.z + d0.z, a0.w + b0.w + c0.w + d0.w);
    float* dst = pb + s * D + chunk * 256 + c * 4;
    atomicAdd(dst + 0, v.x); atomicAdd(dst + 1, v.y);
    atomicAdd(dst + 2, v.z); atomicAdd(dst + 3, v.w);
  }
  __syncthreads();
  // round 2: same for Q -> gsb
#pragma unroll
  for (int s = 0; s < NS; ++s) lp[r4][s][c4] = Q[s];
  __syncthreads();
  for (int k = t; k < 512; k += 256) {
    int s = k >> 6, c = k & 63;
    float4 a0 = lp[0][s][c], b0 = lp[1][s][c], c0 = lp[2][s][c], d0 = lp[3][s][c];
    float4 v = make_float4(a0.x + b0.x + c0.x + d0.x, a0.y + b0.y + c0.y + d0.y,
                           a0.z + b0.z + c0.z + d0.z, a0.w + b0.w + c0.w + d0.w);
    float* dst = gsb + s * D + chunk * 256 + c * 4;
    atomicAdd(dst + 0, v.x); atomicAdd(dst + 1, v.y);
    atomicAdd(dst + 2, v.z); atomicAdd(dst + 3, v.w);
  }
}

// ---- 4: delta = P@Wh.T + GS@Wr2.T + colsum*bw ; alpha inline ; new_state/new_fast
__global__ void __launch_bounds__(256) k4(const float* __restrict__ Ww, const float* __restrict__ bw,
                                          const float* __restrict__ st, const float* __restrict__ fa,
                                          const float* __restrict__ p, const float* __restrict__ gs,
                                          const float* __restrict__ gall,
                                          float* __restrict__ outst, float* __restrict__ outfa,
                                          float* __restrict__ alphaout) {
  int dd = blockIdx.x, t = threadIdx.x;
  const float4* wr = (const float4*)(Ww + (size_t)dd * (2 * D));
  float4 w0 = wr[t], w1 = wr[256 + t], w2 = wr[512 + t], w3 = wr[768 + t];
  const float4* p4 = (const float4*)p;
  const float4* g4 = (const float4*)gs;
  float acc[NS];
#pragma unroll
  for (int s = 0; s < NS; ++s) {
    float4 pa = p4[s * 512 + t], pb2 = p4[s * 512 + 256 + t];
    float4 ga = g4[s * 512 + t], gb = g4[s * 512 + 256 + t];
    acc[s] = w0.x * pa.x + w0.y * pa.y + w0.z * pa.z + w0.w * pa.w
           + w1.x * pb2.x + w1.y * pb2.y + w1.z * pb2.z + w1.w * pb2.w
           + w2.x * ga.x + w2.y * ga.y + w2.z * ga.z + w2.w * ga.w
           + w3.x * gb.x + w3.y * gb.y + w3.z * gb.z + w3.w * gb.w;
  }
#pragma unroll
  for (int off = 32; off > 0; off >>= 1) {
#pragma unroll
    for (int v = 0; v < NS; ++v) acc[v] += __shfl_down(acc[v], off);
  }
  __shared__ float red[32];
  int lane = t & 63, wid = t >> 6;
  if (lane == 0) {
#pragma unroll
    for (int v = 0; v < NS; ++v) red[wid * 8 + v] = acc[v];
  }
  __syncthreads();
  if (t < NS) {
    float tot = red[t] + red[8 + t] + red[16 + t] + red[24 + t];
    float delta = tot + gall[64 + t] * bw[dd];
    float al = 0.02f + 0.98f * (gall[72] * (1.f / (float)BTOT));
    al = fminf(fmaxf(al, 0.f), 1.f);
    size_t idx = (size_t)t * D + dd;
    outst[idx] = (1.f - al) * st[idx] + al * delta;
    outfa[idx] = 0.95f * fa[idx] + 0.05f * delta;
  }
  if (dd == 0 && t == 0) {
    float al = 0.02f + 0.98f * (gall[72] * (1.f / (float)BTOT));
    alphaout[0] = fminf(fmaxf(al, 0.f), 1.f);
  }
}

extern "C" void kernel_launch(void* const* d_in, const int* in_sizes, int n_in,
                              void* d_out, int out_size, void* d_ws, size_t ws_size,
                              hipStream_t stream) {
  const float* h    = (const float*)d_in[0];
  const float* nm   = (const float*)d_in[1];
  const float* keys = (const float*)d_in[2];
  const float* Wr   = (const float*)d_in[3];
  const float* br   = (const float*)d_in[4];
  const float* Wc   = (const float*)d_in[5];
  const float* bc   = (const float*)d_in[6];
  const float* Ww   = (const float*)d_in[7];
  const float* bw   = (const float*)d_in[8];
  const float* st   = (const float*)d_in[9];
  const float* fa   = (const float*)d_in[10];
  float* out = (float*)d_out;
  float* ws  = (float*)d_ws;

  float* sm   = ws + WS_SM;
  float* kpx  = ws + WS_KPX;
  float* gsb  = ws + WS_GS;
  float* pb   = ws + WS_PB;
  float* lb   = ws + WS_LB;
  float* swc  = ws + WS_SWC;
  float* gall = ws + WS_GALL;
  float* attn = out + ATTN_OFF;

  kZ<<<265, 256, 0, stream>>>(st, fa, Wc, ws);
  kA<<<dim3(8, 32), 256, 0, stream>>>(keys, Wr, kpx);
  kC<<<8, 256, 0, stream>>>(keys, br, Wc, sm, lb, swc);
  k1aF<<<512, 256, 0, stream>>>(h, kpx, lb, swc, bc, attn, gall);
  k2n<<<dim3(8, 128), 256, 0, stream>>>(h, nm, sm, attn, out, pb, gsb);
  k4<<<2048, 256, 0, stream>>>(Ww, bw, st, fa, pb, gsb, gall, out + STATE_OFF, out + FAST_OFF,
                               out + ALPHA_OFF);
}

// Round 2
// 444.513 us; speedup vs baseline: 1.1558x; 1.1318x over previous
//
#include <hip/hip_runtime.h>
#include <math.h>

#define D 2048
#define NS 8
#define BTOT 16384

// ---- d_out layout (floats): read[B,D] | attn[B,8] | alpha | new_state[8,D] | new_fast[8,D]
#define ATTN_OFF  ((size_t)BTOT * D)
#define ALPHA_OFF (ATTN_OFF + (size_t)BTOT * NS)
#define STATE_OFF (ALPHA_OFF + 1)
#define FAST_OFF  (STATE_OFF + (size_t)NS * D)

// ---- ws layout (float offsets)
#define WS_SM    0         // 16384 : state+fast
#define WS_KPX   16384     // 18432 : [9][2048] rows 0..7 = keys@Wr, row 8 = wc_h
#define WS_PB    34816     // 16384 : P = attn.T @ (h+nm)  (atomic accum)
#define WS_LB    51200     // 8     : keys @ br
#define WS_SWC   51208     // 8     : Sm @ wc_r
#define WS_GALL  51216     // 48    : [0..35] G tri (attn^T attn), [36..43] colsum, [44] addsum

// ---- Z: sm = state+fast ; zero kpx rows 0..7, P, lb/swc/gall ; copy wc_h to kpx row 8
__global__ void __launch_bounds__(256) kZ(const float* __restrict__ st, const float* __restrict__ fa,
                                          const float* __restrict__ Wc, float* __restrict__ ws) {
  int i = blockIdx.x * 256 + threadIdx.x;
  if (i < 16384) {
    ws[WS_SM + i] = st[i] + fa[i];
  } else if (i < 32768) {
    ws[WS_KPX + (i - 16384)] = 0.f;                       // kpx rows 0..7
  } else if (i < 34816) {
    ws[WS_KPX + 16384 + (i - 32768)] = Wc[i - 32768];     // kpx row 8 = wc_h
  } else if (i < 51200) {
    ws[WS_PB + (i - 34816)] = 0.f;
  } else if (i < 51264) {
    ws[WS_LB + (i - 51200)] = 0.f;                        // lb(8)|swc(8)|gall(48)
  }
}

// ---- A: kpx[s][e] += sum_{d in chunk} keys[s][d] * Wr[d][e]   (atomic)
__global__ void __launch_bounds__(256) kA(const float* __restrict__ keys,
                                          const float* __restrict__ Wr,
                                          float* __restrict__ kpx) {
  int e = blockIdx.x * 256 + threadIdx.x;
  int d0 = blockIdx.y * 64;
  float acc[NS] = {0.f,0.f,0.f,0.f,0.f,0.f,0.f,0.f};
  for (int d = d0; d < d0 + 64; ++d) {
    float wv = Wr[(size_t)d * D + e];
#pragma unroll
    for (int s = 0; s < NS; ++s) acc[s] += keys[s * D + d] * wv;
  }
#pragma unroll
  for (int s = 0; s < NS; ++s) atomicAdd(&kpx[s * D + e], acc[s]);
}

// ---- C: lb[s] = keys[s].br ; swc[s] = Sm[s].wc_r   (8 blocks, atomic accum)
__global__ void __launch_bounds__(256) kC(const float* __restrict__ keys,
                                          const float* __restrict__ br,
                                          const float* __restrict__ Wc,
                                          const float* __restrict__ sm,
                                          float* __restrict__ lb, float* __restrict__ swc) {
  int t = threadIdx.x;
  int idx = blockIdx.x * 256 + t;
  float brv = br[idx];
  float wcr = Wc[D + idx];
  float v[16];
#pragma unroll
  for (int s = 0; s < NS; ++s) {
    v[s]     = keys[s * D + idx] * brv;
    v[8 + s] = sm[s * D + idx] * wcr;
  }
#pragma unroll
  for (int off = 32; off > 0; off >>= 1) {
#pragma unroll
    for (int k = 0; k < 16; ++k) v[k] += __shfl_down(v[k], off);
  }
  __shared__ float red[4 * 16];
  int lane = t & 63, wid = t >> 6;
  if (lane == 0) {
#pragma unroll
    for (int k = 0; k < 16; ++k) red[wid * 16 + k] = v[k];
  }
  __syncthreads();
  if (t < 16) {
    float tot = red[t] + red[16 + t] + red[32 + t] + red[48 + t];
    if (t < 8) atomicAdd(&lb[t], tot); else atomicAdd(&swc[t - 8], tot);
  }
}

// ---- 1: LDS-free fused logits + softmax + attn + G/colsum/addsum.
//  16 lanes per row (4 rows/wave, 16 rows/block, 1024 blocks).
//  kpx (73.7 KB) read directly from global: L2-resident, 256 B unique per wave-instr.
__global__ void __launch_bounds__(256, 4) k1r(const float* __restrict__ h,
                                              const float* __restrict__ kpx,
                                              const float* __restrict__ lb, const float* __restrict__ swc,
                                              const float* __restrict__ bc,
                                              float* __restrict__ attn, float* __restrict__ gall) {
  int t = threadIdx.x;
  int q = t & 15;
  int row = blockIdx.x * 16 + (t >> 4);
  const float4* h4 = (const float4*)h + (size_t)row * 512;
  const float4* kp4 = (const float4*)kpx;
  float acc[9] = {0.f,0.f,0.f,0.f,0.f,0.f,0.f,0.f,0.f};
#pragma unroll 4
  for (int j = 0; j < 32; ++j) {
    float4 hv = h4[j * 16 + q];
#pragma unroll
    for (int s = 0; s < 9; ++s) {
      float4 kv = kp4[s * 512 + j * 16 + q];
      acc[s] += hv.x * kv.x + hv.y * kv.y + hv.z * kv.z + hv.w * kv.w;
    }
  }
  // reduce across the 16 col-lanes
#pragma unroll
  for (int off = 1; off <= 8; off <<= 1) {
#pragma unroll
    for (int s = 0; s < 9; ++s) acc[s] += __shfl_xor(acc[s], off);
  }
  // softmax (redundant on all 16 lanes of the group)
  float lg[8]; float m = -1e30f;
#pragma unroll
  for (int s = 0; s < NS; ++s) { lg[s] = acc[s] + lb[s]; m = fmaxf(m, lg[s]); }
  float sum = 0.f;
#pragma unroll
  for (int s = 0; s < NS; ++s) { lg[s] = expf(lg[s] - m); sum += lg[s]; }
  float inv = 1.f / sum;
  float x = acc[8] + bc[0];
#pragma unroll
  for (int s = 0; s < NS; ++s) { lg[s] *= inv; x += lg[s] * swc[s]; }
  float add = 1.f / (1.f + expf(-x));
  if (q == 0) ((float4*)(attn + (size_t)row * NS))[0] = make_float4(lg[0], lg[1], lg[2], lg[3]);
  if (q == 1) ((float4*)(attn + (size_t)row * NS))[1] = make_float4(lg[4], lg[5], lg[6], lg[7]);
  // per-row stats: G tri (36) | colsum (8) | add (1); sum the wave's 4 distinct rows
  float v[45];
  {
    int c = 0;
#pragma unroll
    for (int i = 0; i < NS; ++i)
#pragma unroll
      for (int j = i; j < NS; ++j) v[c++] = lg[i] * lg[j];
  }
#pragma unroll
  for (int s = 0; s < NS; ++s) v[36 + s] = lg[s];
  v[44] = add;
#pragma unroll
  for (int off = 16; off <= 32; off <<= 1) {
#pragma unroll
    for (int k = 0; k < 45; ++k) v[k] += __shfl_xor(v[k], off);
  }
  // NOTE: values are uniform within each 16-lane group, so xor16/32 sums the 4 rows once each.
  __shared__ float red[4][45];
  int lane = t & 63, w = t >> 6;
  if (lane == 0) {
#pragma unroll
    for (int k = 0; k < 45; ++k) red[w][k] = v[k];
  }
  __syncthreads();
  if (t < 45) {
    float tot = red[0][t] + red[1][t] + red[2][t] + red[3][t];
    atomicAdd(&gall[t], tot);
  }
}

static __device__ __forceinline__ float4 f4fma(float s, float4 a, float4 c) {
  c.x += s * a.x; c.y += s * a.y; c.z += s * a.z; c.w += s * a.w; return c;
}

// ---- 2: read = attn @ Sm (streamed), P += attn.T @ (h+nm).
//  Grid (16 col-chunks x 64 row-chunks) = 1024 blocks, 4/CU; 32-lane column groups, 8 rows in flight.
__global__ void __launch_bounds__(256, 4) k2n(const float* __restrict__ h, const float* __restrict__ nm,
                                              const float* __restrict__ sm, const float* __restrict__ attn,
                                              float* __restrict__ readout, float* __restrict__ pb) {
  __shared__ float4 lp[8][NS][32];   // 32 KB
  int t = threadIdx.x;
  int c4 = t & 31, r4 = t >> 5;
  int chunk = blockIdx.x, rc = blockIdx.y;
  int fbase = chunk * 32 + c4;            // float4 index within row [0,512)
  const float4* sm4 = (const float4*)sm;
  float4 S[NS];
#pragma unroll
  for (int s = 0; s < NS; ++s) S[s] = sm4[s * 512 + fbase];
  float4 P[NS];
#pragma unroll
  for (int s = 0; s < NS; ++s) P[s] = make_float4(0.f, 0.f, 0.f, 0.f);
  int rowbase = rc * 256;
#pragma unroll 2
  for (int it = 0; it < 32; ++it) {
    int row = rowbase + it * 8 + r4;
    float4 hv = ((const float4*)h)[(size_t)row * 512 + fbase];
    float4 nv = ((const float4*)nm)[(size_t)row * 512 + fbase];
    const float* ar = attn + (size_t)row * NS;
    float a[NS];
#pragma unroll
    for (int s = 0; s < NS; ++s) a[s] = ar[s];
    float4 wv = make_float4(hv.x + nv.x, hv.y + nv.y, hv.z + nv.z, hv.w + nv.w);
    float4 rd = make_float4(0.f, 0.f, 0.f, 0.f);
#pragma unroll
    for (int s = 0; s < NS; ++s) {
      rd = f4fma(a[s], S[s], rd);
      P[s] = f4fma(a[s], wv, P[s]);
    }
    ((float4*)readout)[(size_t)row * 512 + fbase] = rd;
  }
#pragma unroll
  for (int s = 0; s < NS; ++s) lp[r4][s][c4] = P[s];
  __syncthreads();
  {
    int s = t >> 5, c = t & 31;
    float4 v = make_float4(0.f, 0.f, 0.f, 0.f);
#pragma unroll
    for (int g = 0; g < 8; ++g) {
      float4 u = lp[g][s][c];
      v.x += u.x; v.y += u.y; v.z += u.z; v.w += u.w;
    }
    float* dst = pb + s * D + chunk * 128 + c * 4;
    atomicAdd(dst + 0, v.x); atomicAdd(dst + 1, v.y);
    atomicAdd(dst + 2, v.z); atomicAdd(dst + 3, v.w);
  }
}

// ---- 4: delta[s][dd] = P[s].Ww1[dd] + sum_sp G[s,sp]*(Sm[sp].Ww2[dd]) + colsum[s]*bw[dd]
//         then new_state/new_fast; alpha inline.
__global__ void __launch_bounds__(256) k4(const float* __restrict__ Ww, const float* __restrict__ bw,
                                          const float* __restrict__ st, const float* __restrict__ fa,
                                          const float* __restrict__ p, const float* __restrict__ sm,
                                          const float* __restrict__ gall,
                                          float* __restrict__ outst, float* __restrict__ outfa,
                                          float* __restrict__ alphaout) {
  int dd = blockIdx.x, t = threadIdx.x;
  const float4* wr = (const float4*)(Ww + (size_t)dd * (2 * D));
  float4 w0 = wr[t], w1 = wr[256 + t], w2 = wr[512 + t], w3 = wr[768 + t];
  const float4* p4 = (const float4*)p;
  const float4* s4 = (const float4*)sm;
  float acc[16];
#pragma unroll
  for (int s = 0; s < NS; ++s) {
    float4 pa = p4[s * 512 + t], pb2 = p4[s * 512 + 256 + t];
    float4 sa = s4[s * 512 + t], sb = s4[s * 512 + 256 + t];
    acc[s] = w0.x * pa.x + w0.y * pa.y + w0.z * pa.z + w0.w * pa.w
           + w1.x * pb2.x + w1.y * pb2.y + w1.z * pb2.z + w1.w * pb2.w;
    acc[8 + s] = w2.x * sa.x + w2.y * sa.y + w2.z * sa.z + w2.w * sa.w
               + w3.x * sb.x + w3.y * sb.y + w3.z * sb.z + w3.w * sb.w;
  }
#pragma unroll
  for (int off = 32; off > 0; off >>= 1) {
#pragma unroll
    for (int k = 0; k < 16; ++k) acc[k] += __shfl_down(acc[k], off);
  }
  __shared__ float red[4][16];
  __shared__ float red2[16];
  int lane = t & 63, wid = t >> 6;
  if (lane == 0) {
#pragma unroll
    for (int k = 0; k < 16; ++k) red[wid][k] = acc[k];
  }
  __syncthreads();
  if (t < 16) red2[t] = red[0][t] + red[1][t] + red[2][t] + red[3][t];
  __syncthreads();
  if (t < NS) {
    float delta = red2[t];
#pragma unroll
    for (int sp = 0; sp < NS; ++sp) {
      int i = t < sp ? t : sp;
      int j = t < sp ? sp : t;
      int idx = i * 8 - (i * (i - 1)) / 2 + (j - i);
      delta += gall[idx] * red2[8 + sp];
    }
    delta += gall[36 + t] * bw[dd];
    float al = 0.02f + 0.98f * (gall[44] * (1.f / (float)BTOT));
    al = fminf(fmaxf(al, 0.f), 1.f);
    size_t idx2 = (size_t)t * D + dd;
    outst[idx2] = (1.f - al) * st[idx2] + al * delta;
    outfa[idx2] = 0.95f * fa[idx2] + 0.05f * delta;
  }
  if (dd == 0 && t == 0) {
    float al = 0.02f + 0.98f * (gall[44] * (1.f / (float)BTOT));
    alphaout[0] = fminf(fmaxf(al, 0.f), 1.f);
  }
}

extern "C" void kernel_launch(void* const* d_in, const int* in_sizes, int n_in,
                              void* d_out, int out_size, void* d_ws, size_t ws_size,
                              hipStream_t stream) {
  const float* h    = (const float*)d_in[0];
  const float* nm   = (const float*)d_in[1];
  const float* keys = (const float*)d_in[2];
  const float* Wr   = (const float*)d_in[3];
  const float* br   = (const float*)d_in[4];
  const float* Wc   = (const float*)d_in[5];
  const float* bc   = (const float*)d_in[6];
  const float* Ww   = (const float*)d_in[7];
  const float* bw   = (const float*)d_in[8];
  const float* st   = (const float*)d_in[9];
  const float* fa   = (const float*)d_in[10];
  float* out = (float*)d_out;
  float* ws  = (float*)d_ws;

  float* sm   = ws + WS_SM;
  float* kpx  = ws + WS_KPX;
  float* pb   = ws + WS_PB;
  float* lb   = ws + WS_LB;
  float* swc  = ws + WS_SWC;
  float* gall = ws + WS_GALL;
  float* attn = out + ATTN_OFF;

  kZ<<<201, 256, 0, stream>>>(st, fa, Wc, ws);
  kA<<<dim3(8, 32), 256, 0, stream>>>(keys, Wr, kpx);
  kC<<<8, 256, 0, stream>>>(keys, br, Wc, sm, lb, swc);
  k1r<<<1024, 256, 0, stream>>>(h, kpx, lb, swc, bc, attn, gall);
  k2n<<<dim3(16, 64), 256, 0, stream>>>(h, nm, sm, attn, out, pb);
  k4<<<2048, 256, 0, stream>>>(Ww, bw, st, fa, pb, sm, gall, out + STATE_OFF, out + FAST_OFF,
                               out + ALPHA_OFF);
}